// Round 6
// baseline (370.601 us; speedup 1.0000x reference)
//
#include <hip/hip_runtime.h>

// Discriminator GCN: x2 = sigmoid(GCN2(sigmoid(GCN1(x)))), N=4096, E=262144.
// Layer 1 as two bf16 MFMA GEMMs (dense S). GEMM2 fuses bias+sigmoid+W2-matvec.
// GEMM: faithful m201-style 8-phase/2-tile schedule: per phase
//   {ds_read this phase's frags; 2x global_load_lds; [vmcnt]; barrier;
//    lgkmcnt(0); setprio(1); 16 MFMA; setprio(0); barrier}
// with counted vmcnt(4)/vmcnt(2) once each per K-tile; B-frags live across phases.

typedef __attribute__((ext_vector_type(8))) short bf16x8;
typedef __attribute__((ext_vector_type(4))) float f32x4;

#define NN 4096
#define NT 64   // K tiles of 64

__device__ __forceinline__ unsigned f2bf(float f) {
  unsigned u = __float_as_uint(f);
  return (u + 0x7FFFu + ((u >> 16) & 1u)) >> 16;   // RNE f32 -> bf16
}

#define GLDS(g, l) __builtin_amdgcn_global_load_lds(                      \
    (const __attribute__((address_space(1))) void*)(g),                   \
    (__attribute__((address_space(3))) void*)(l), 16, 0, 0)

// ---------------- small graph kernels ----------------

__global__ void init_deg_kernel(float* deg) {
  int v = blockIdx.x * 256 + threadIdx.x;
  if (v < NN) deg[v] = 1.0f;
}

__global__ void count_deg_kernel(const int* __restrict__ dst, int E, float* deg) {
  int e = blockIdx.x * 256 + threadIdx.x;
  if (e < E) atomicAdd(&deg[dst[e]], 1.0f);
}

__global__ void dinv_kernel(const float* __restrict__ deg, float* __restrict__ dinv) {
  int v = blockIdx.x * 256 + threadIdx.x;
  if (v < NN) dinv[v] = rsqrtf(deg[v]);
}

__global__ void diag_kernel(const float* __restrict__ dinv, float* __restrict__ S) {
  int v = blockIdx.x * 256 + threadIdx.x;
  if (v < NN) { float d = dinv[v]; S[(size_t)v * NN + v] = d * d; }
}

__global__ void scatter_S_kernel(const int* __restrict__ src, const int* __restrict__ dst,
                                 int E, const float* __restrict__ dinv, float* __restrict__ S) {
  int e = blockIdx.x * 256 + threadIdx.x;
  if (e < E) {
    int s = src[e], d = dst[e];
    atomicAdd(&S[(size_t)d * NN + s], dinv[s] * dinv[d]);
  }
}

// ---------------- casts ----------------

__global__ void cast_kernel(const float* __restrict__ in, unsigned short* __restrict__ out, int n) {
  int i = (blockIdx.x * 256 + threadIdx.x) * 8;
  if (i >= n) return;
  const float4* p = (const float4*)(in + i);
  float4 a = p[0], b = p[1];
  uint4 o;
  o.x = f2bf(a.x) | (f2bf(a.y) << 16);
  o.y = f2bf(a.z) | (f2bf(a.w) << 16);
  o.z = f2bf(b.x) | (f2bf(b.y) << 16);
  o.w = f2bf(b.z) | (f2bf(b.w) << 16);
  *(uint4*)(out + i) = o;
}

__global__ void transpose_cast_kernel(const float* __restrict__ W, unsigned short* __restrict__ WT) {
  __shared__ float tile[32][33];
  int bx = blockIdx.x * 32, by = blockIdx.y * 32;
  int tx = threadIdx.x, ty = threadIdx.y;
#pragma unroll
  for (int i = 0; i < 32; i += 8)
    tile[ty + i][tx] = W[(size_t)(by + ty + i) * NN + bx + tx];
  __syncthreads();
#pragma unroll
  for (int i = 0; i < 32; i += 8)
    WT[(size_t)(bx + ty + i) * NN + by + tx] = (unsigned short)f2bf(tile[tx][ty + i]);
}

// ------------- 256x256 bf16 GEMM: C[M][N] = A[M][K] * BT[N][K]^T -------------
// LDS per buf (64KB): A [256][64] bf16 rows 128B, 16B-granule XOR swizzle; B at +32KB.
// Pieces (64 rows = 8KB): A0..A3, B0..B3; pure double-buffer (stage only into buf^1).
// Phases per K-tile (m201 template): P(mh,kk), 16 MFMA each; bk0/bk1 read once,
// reused at P3/P4. Stage: P1:B0,B1  P2:B2,B3  P3:A0,A2  P4:A1,A3 (of t+1).
// vmcnt(4) @P2 entry-barrier: A1,A3(t) landed (issued t-1.P4) before P3 reads.
// vmcnt(2) @P4 entry-barrier: 6 early pieces of t+1 landed before t+1.P1/P2 read.
// Per-wave outstanding: 2 -> 4 -> 6(wait4) -> 6 -> 8(wait2); never drained to 0.

template <int EPI>  // 0: bf16 C store; 1: fused sigmoid(acc+b1)*W2 -> atomic h2
__global__ __launch_bounds__(512, 2) void gemm256_kernel(
    const unsigned short* __restrict__ A, const unsigned short* __restrict__ BT,
    unsigned short* __restrict__ C, const float* __restrict__ bias,
    const float* __restrict__ W2, float* __restrict__ h2) {
  __shared__ __align__(16) char smem[131072];
  const int tid = threadIdx.x;
  const int lane = tid & 63, wid = tid >> 6;
  const int wr = wid >> 2, wc = wid & 3;     // 2x4 wave grid; wave owns 128x64 of C

  const int bid = blockIdx.x;
  const int swz = (bid & 7) * 32 + (bid >> 3);   // XCD-aware remap (256 = 8*32)
  const int rowBase = (swz >> 4) * 256;
  const int colBase = (swz & 15) * 256;

  // staging source (per-thread, pre-swizzled column so linear LDS dest = swizzled layout)
  const int srow = tid >> 3;                              // 0..63 within a piece
  const int scolb = ((tid & 7) << 4) ^ ((srow & 7) << 4);
  const unsigned short* pA = A + (size_t)(rowBase + srow) * NN + (scolb >> 1);
  const unsigned short* pB = BT + (size_t)(colBase + srow) * NN + (scolb >> 1);

  // ds_read swizzled column constants
  const int rl = lane & 15;
  const int c0 = ((lane >> 4) << 4) ^ ((lane & 7) << 4);  // kk=0 physical col byte
  const int c1 = c0 ^ 64;                                  // kk=1
  const int aoff = (wr * 128 + rl) * 128;          // A row byte base (mh0,m=0)
  const int boff = 32768 + (wc * 64 + rl) * 128;   // B row byte base

  f32x4 acc[8][4] = {};
  bf16x8 bk0[4], bk1[4], afA[4], afB[4];

  // prologue: stage tile0 -> buf0, order B0..B3,A0,A2,A1,A3; first 6 guarded
  {
    char* w0 = smem + (wid << 10);
    GLDS(pB + (size_t)0 * 64 * NN, w0 + 32768 + 0 * 8192);
    GLDS(pB + (size_t)1 * 64 * NN, w0 + 32768 + 1 * 8192);
    GLDS(pB + (size_t)2 * 64 * NN, w0 + 32768 + 2 * 8192);
    GLDS(pB + (size_t)3 * 64 * NN, w0 + 32768 + 3 * 8192);
    GLDS(pA + (size_t)0 * 64 * NN, w0 + 0 * 8192);
    GLDS(pA + (size_t)2 * 64 * NN, w0 + 2 * 8192);
    GLDS(pA + (size_t)1 * 64 * NN, w0 + 1 * 8192);
    GLDS(pA + (size_t)3 * 64 * NN, w0 + 3 * 8192);
    asm volatile("s_waitcnt vmcnt(2)" ::: "memory");
    __builtin_amdgcn_s_barrier();
  }

#pragma unroll 2
  for (int t = 0; t < NT; ++t) {
    const char* lb = smem + ((t & 1) << 16);
    char* st = smem + (((t & 1) ^ 1) << 16) + (wid << 10);
    // t=NT-1 prefetch runs one row past the operand end: stays inside adjacent
    // workspace regions (audited), never consumed.
    const unsigned short* s1A = pA + (size_t)(t + 1) * 64;
    const unsigned short* s1B = pB + (size_t)(t + 1) * 64;

    // ---- P1 (mh0,k0): read afA,bk0; stage B0,B1(t+1) ----
#pragma unroll
    for (int m = 0; m < 4; ++m) afA[m] = *(const bf16x8*)(lb + aoff + m * 2048 + c0);
#pragma unroll
    for (int n = 0; n < 4; ++n) bk0[n] = *(const bf16x8*)(lb + boff + n * 2048 + c0);
    GLDS(s1B + (size_t)0 * 64 * NN, st + 32768 + 0 * 8192);
    GLDS(s1B + (size_t)1 * 64 * NN, st + 32768 + 1 * 8192);
    __builtin_amdgcn_s_barrier();
    asm volatile("s_waitcnt lgkmcnt(0)" ::: "memory");
    __builtin_amdgcn_sched_barrier(0);
    __builtin_amdgcn_s_setprio(1);
#pragma unroll
    for (int m = 0; m < 4; ++m)
#pragma unroll
      for (int n = 0; n < 4; ++n)
        acc[m][n] = __builtin_amdgcn_mfma_f32_16x16x32_bf16(afA[m], bk0[n], acc[m][n], 0, 0, 0);
    __builtin_amdgcn_s_setprio(0);
    __builtin_amdgcn_s_barrier();

    // ---- P2 (mh0,k1): read afB,bk1; stage B2,B3(t+1); vmcnt(4) guards A1,A3(t) ----
#pragma unroll
    for (int m = 0; m < 4; ++m) afB[m] = *(const bf16x8*)(lb + aoff + m * 2048 + c1);
#pragma unroll
    for (int n = 0; n < 4; ++n) bk1[n] = *(const bf16x8*)(lb + boff + n * 2048 + c1);
    GLDS(s1B + (size_t)2 * 64 * NN, st + 32768 + 2 * 8192);
    GLDS(s1B + (size_t)3 * 64 * NN, st + 32768 + 3 * 8192);
    asm volatile("s_waitcnt vmcnt(4)" ::: "memory");
    __builtin_amdgcn_s_barrier();
    asm volatile("s_waitcnt lgkmcnt(0)" ::: "memory");
    __builtin_amdgcn_sched_barrier(0);
    __builtin_amdgcn_s_setprio(1);
#pragma unroll
    for (int m = 0; m < 4; ++m)
#pragma unroll
      for (int n = 0; n < 4; ++n)
        acc[m][n] = __builtin_amdgcn_mfma_f32_16x16x32_bf16(afB[m], bk1[n], acc[m][n], 0, 0, 0);
    __builtin_amdgcn_s_setprio(0);
    __builtin_amdgcn_s_barrier();

    // ---- P3 (mh1,k0): read afA; reuse bk0; stage A0,A2(t+1) ----
#pragma unroll
    for (int m = 0; m < 4; ++m) afA[m] = *(const bf16x8*)(lb + aoff + (4 + m) * 2048 + c0);
    GLDS(s1A + (size_t)0 * 64 * NN, st + 0 * 8192);
    GLDS(s1A + (size_t)2 * 64 * NN, st + 2 * 8192);
    __builtin_amdgcn_s_barrier();
    asm volatile("s_waitcnt lgkmcnt(0)" ::: "memory");
    __builtin_amdgcn_sched_barrier(0);
    __builtin_amdgcn_s_setprio(1);
#pragma unroll
    for (int m = 0; m < 4; ++m)
#pragma unroll
      for (int n = 0; n < 4; ++n)
        acc[4 + m][n] = __builtin_amdgcn_mfma_f32_16x16x32_bf16(afA[m], bk0[n], acc[4 + m][n], 0, 0, 0);
    __builtin_amdgcn_s_setprio(0);
    __builtin_amdgcn_s_barrier();

    // ---- P4 (mh1,k1): read afB; reuse bk1; stage A1,A3(t+1); vmcnt(2) guards t+1 early ----
#pragma unroll
    for (int m = 0; m < 4; ++m) afB[m] = *(const bf16x8*)(lb + aoff + (4 + m) * 2048 + c1);
    GLDS(s1A + (size_t)1 * 64 * NN, st + 1 * 8192);
    GLDS(s1A + (size_t)3 * 64 * NN, st + 3 * 8192);
    asm volatile("s_waitcnt vmcnt(2)" ::: "memory");
    __builtin_amdgcn_s_barrier();
    asm volatile("s_waitcnt lgkmcnt(0)" ::: "memory");
    __builtin_amdgcn_sched_barrier(0);
    __builtin_amdgcn_s_setprio(1);
#pragma unroll
    for (int m = 0; m < 4; ++m)
#pragma unroll
      for (int n = 0; n < 4; ++n)
        acc[4 + m][n] = __builtin_amdgcn_mfma_f32_16x16x32_bf16(afB[m], bk1[n], acc[4 + m][n], 0, 0, 0);
    __builtin_amdgcn_s_setprio(0);
    __builtin_amdgcn_s_barrier();
  }

  // ---- epilogue ----
  const int orow = rowBase + wr * 128 + (lane >> 4) * 4;
  const int ocol = colBase + wc * 64 + (lane & 15);
  if (EPI == 0) {
#pragma unroll
    for (int n = 0; n < 4; ++n) {
      int ccol = ocol + n * 16;
#pragma unroll
      for (int m = 0; m < 8; ++m) {
#pragma unroll
        for (int i = 0; i < 4; ++i) {
          C[(size_t)(orow + m * 16 + i) * NN + ccol] = (unsigned short)f2bf(acc[m][n][i]);
        }
      }
    }
  } else {
    // x1 = sigmoid(acc + b1[col]); h2[row] += sum_col x1*W2[col]
    float bv[4], wv[4];
#pragma unroll
    for (int n = 0; n < 4; ++n) { bv[n] = bias[ocol + n * 16]; wv[n] = W2[ocol + n * 16]; }
#pragma unroll
    for (int m = 0; m < 8; ++m) {
#pragma unroll
      for (int i = 0; i < 4; ++i) {
        float s = 0.0f;
#pragma unroll
        for (int n = 0; n < 4; ++n) {
          float x = 1.0f / (1.0f + __expf(-(acc[m][n][i] + bv[n])));
          s += x * wv[n];
        }
        s += __shfl_xor(s, 1);
        s += __shfl_xor(s, 2);
        s += __shfl_xor(s, 4);
        s += __shfl_xor(s, 8);
        if ((lane & 15) == 0) atomicAdd(&h2[orow + m * 16 + i], s);
      }
    }
  }
}

// ---------------- layer 2 tail ----------------

__global__ void init_t_kernel(const float* __restrict__ dinv, const float* __restrict__ h2,
                              const float* __restrict__ b2, float* __restrict__ tacc) {
  int v = blockIdx.x * 256 + threadIdx.x;
  if (v < NN) tacc[v] = dinv[v] * dinv[v] * h2[v] + b2[0];
}

__global__ void scatter_t_kernel(const int* __restrict__ src, const int* __restrict__ dst,
                                 int E, const float* __restrict__ dinv,
                                 const float* __restrict__ h2, float* __restrict__ tacc) {
  int e = blockIdx.x * 256 + threadIdx.x;
  if (e < E) {
    int s = src[e], d = dst[e];
    atomicAdd(&tacc[d], dinv[s] * dinv[d] * h2[s]);
  }
}

__global__ void final_kernel(const float* __restrict__ tacc, float* __restrict__ out) {
  int v = blockIdx.x * 256 + threadIdx.x;
  if (v < NN) out[v] = 1.0f / (1.0f + __expf(-tacc[v]));
}

// ---------------- launch ----------------

extern "C" void kernel_launch(void* const* d_in, const int* in_sizes, int n_in,
                              void* d_out, int out_size, void* d_ws, size_t ws_size,
                              hipStream_t stream) {
  const float* x  = (const float*)d_in[0];
  const int*   ei = (const int*)d_in[1];
  const float* W1 = (const float*)d_in[2];
  const float* b1 = (const float*)d_in[3];
  const float* W2 = (const float*)d_in[4];
  const float* b2 = (const float*)d_in[5];
  float* out = (float*)d_out;
  const int E = in_sizes[1] / 2;
  const int* esrc = ei;
  const int* edst = ei + E;

  char* w = (char*)d_ws;
  float*          Sf  = (float*)w;                                  // [0,64M) f32 dense S
  unsigned short* H1T = (unsigned short*)w;                         // [0,32M)  (after Sf dead)
  unsigned short* W1T = (unsigned short*)(w + (size_t)(32u << 20)); // [32M,64M)
  unsigned short* Sbf = (unsigned short*)(w + (size_t)(64u << 20)); // [64M,96M)
  unsigned short* Xbf = (unsigned short*)(w + (size_t)(96u << 20)); // [96M,128M)
  float* deg  = (float*)(w + (size_t)(128u << 20));
  float* dinv = deg + 4096;
  float* h2   = deg + 8192;
  float* tacc = deg + 12288;

  // graph normalization
  init_deg_kernel<<<16, 256, 0, stream>>>(deg);
  count_deg_kernel<<<(E + 255) / 256, 256, 0, stream>>>(edst, E, deg);
  dinv_kernel<<<16, 256, 0, stream>>>(deg, dinv);

  // dense S (f32, atomics sum duplicate edges), then cast to bf16
  hipMemsetAsync(Sf, 0, (size_t)64 << 20, stream);
  hipMemsetAsync(h2, 0, 4096 * sizeof(float), stream);
  diag_kernel<<<16, 256, 0, stream>>>(dinv, Sf);
  scatter_S_kernel<<<(E + 255) / 256, 256, 0, stream>>>(esrc, edst, E, dinv, Sf);
  cast_kernel<<<8192, 256, 0, stream>>>(Sf, Sbf, NN * NN);

  // operand preparation
  cast_kernel<<<8192, 256, 0, stream>>>(x, Xbf, NN * NN);
  transpose_cast_kernel<<<dim3(128, 128), dim3(32, 8), 0, stream>>>(W1, W1T);

  // layer 1: GEMM1 (H1T), then GEMM2 with fused sigmoid + W2 matvec -> h2
  gemm256_kernel<0><<<256, 512, 0, stream>>>(W1T, Xbf, H1T, nullptr, nullptr, nullptr);
  gemm256_kernel<1><<<256, 512, 0, stream>>>(Sbf, H1T, nullptr, b1, W2, h2);

  // layer 2 tail: scalar aggregation + sigmoid
  init_t_kernel<<<16, 256, 0, stream>>>(dinv, h2, b2, tacc);
  scatter_t_kernel<<<(E + 255) / 256, 256, 0, stream>>>(esrc, edst, E, dinv, h2, tacc);
  final_kernel<<<16, 256, 0, stream>>>(tacc, out);
}

// Round 7
// 352.638 us; speedup vs baseline: 1.0509x; 1.0509x over previous
//
#include <hip/hip_runtime.h>

// Discriminator GCN: x2 = sigmoid(GCN2(sigmoid(GCN1(x)))), N=4096, E=262144.
// Layer 1 as two bf16 MFMA GEMMs (dense S). GEMM2 fuses bias+sigmoid+W2-matvec.
// GEMM: 256x256 tile, BK=64, 8 waves, register software pipeline (r5 host) with
// ALL 8 staging loads issued at tile start (full-tile lead >> HBM latency):
//   t.start: GLDS x8 (t+1 -> buf^1; buf^1 fully dead since t-1.P3end fence)
//   P1: MFMA(mh0,k0) [regs from t-1.P4]; read P2 frags; vmcnt(8)+barrier
//   P2: MFMA(mh0,k1); read P3 frags
//   P3: MFMA(mh1,k0); read P4 frags; lgkmcnt(0)+vmcnt(2)+barrier
//   P4: preload next P1 frags from buf^1; MFMA(mh1,k1)
// vmcnt(8): t's A1,A3 landed (issued 1 tile ago). vmcnt(2): t+1 early-6 landed.

typedef __attribute__((ext_vector_type(8))) short bf16x8;
typedef __attribute__((ext_vector_type(4))) float f32x4;

#define NN 4096
#define NT 64   // K tiles of 64

__device__ __forceinline__ unsigned f2bf(float f) {
  unsigned u = __float_as_uint(f);
  return (u + 0x7FFFu + ((u >> 16) & 1u)) >> 16;   // RNE f32 -> bf16
}

#define GLDS(g, l) __builtin_amdgcn_global_load_lds(                      \
    (const __attribute__((address_space(1))) void*)(g),                   \
    (__attribute__((address_space(3))) void*)(l), 16, 0, 0)

// ---------------- small graph kernels ----------------

__global__ void init_deg_kernel(float* deg) {
  int v = blockIdx.x * 256 + threadIdx.x;
  if (v < NN) deg[v] = 1.0f;
}

__global__ void count_deg_kernel(const int* __restrict__ dst, int E, float* deg) {
  int e = blockIdx.x * 256 + threadIdx.x;
  if (e < E) atomicAdd(&deg[dst[e]], 1.0f);
}

__global__ void dinv_kernel(const float* __restrict__ deg, float* __restrict__ dinv) {
  int v = blockIdx.x * 256 + threadIdx.x;
  if (v < NN) dinv[v] = rsqrtf(deg[v]);
}

__global__ void diag_kernel(const float* __restrict__ dinv, float* __restrict__ S) {
  int v = blockIdx.x * 256 + threadIdx.x;
  if (v < NN) { float d = dinv[v]; S[(size_t)v * NN + v] = d * d; }
}

__global__ void scatter_S_kernel(const int* __restrict__ src, const int* __restrict__ dst,
                                 int E, const float* __restrict__ dinv, float* __restrict__ S) {
  int e = blockIdx.x * 256 + threadIdx.x;
  if (e < E) {
    int s = src[e], d = dst[e];
    atomicAdd(&S[(size_t)d * NN + s], dinv[s] * dinv[d]);
  }
}

// ---------------- casts ----------------

__global__ void cast_kernel(const float* __restrict__ in, unsigned short* __restrict__ out, int n) {
  int i = (blockIdx.x * 256 + threadIdx.x) * 8;
  if (i >= n) return;
  const float4* p = (const float4*)(in + i);
  float4 a = p[0], b = p[1];
  uint4 o;
  o.x = f2bf(a.x) | (f2bf(a.y) << 16);
  o.y = f2bf(a.z) | (f2bf(a.w) << 16);
  o.z = f2bf(b.x) | (f2bf(b.y) << 16);
  o.w = f2bf(b.z) | (f2bf(b.w) << 16);
  *(uint4*)(out + i) = o;
}

__global__ void transpose_cast_kernel(const float* __restrict__ W, unsigned short* __restrict__ WT) {
  __shared__ float tile[32][33];
  int bx = blockIdx.x * 32, by = blockIdx.y * 32;
  int tx = threadIdx.x, ty = threadIdx.y;
#pragma unroll
  for (int i = 0; i < 32; i += 8)
    tile[ty + i][tx] = W[(size_t)(by + ty + i) * NN + bx + tx];
  __syncthreads();
#pragma unroll
  for (int i = 0; i < 32; i += 8)
    WT[(size_t)(bx + ty + i) * NN + by + tx] = (unsigned short)f2bf(tile[tx][ty + i]);
}

// ------------- 256x256 bf16 GEMM: C[M][N] = A[M][K] * BT[N][K]^T -------------
// LDS per buf (64KB): A [256][64] bf16 rows 128B, 16B-granule XOR swizzle; B at +32KB.
// Pieces (64 rows = 8KB): A0..A3, B0..B3; staged piece-order B0..B3,A0,A2 | A1,A3
// so vmcnt(2) (oldest-first) certifies early-6 while A-odd may stay in flight.

template <int EPI>  // 0: bf16 C store; 1: fused sigmoid(acc+b1)*W2 -> atomic h2
__global__ __launch_bounds__(512, 2) void gemm256_kernel(
    const unsigned short* __restrict__ A, const unsigned short* __restrict__ BT,
    unsigned short* __restrict__ C, const float* __restrict__ bias,
    const float* __restrict__ W2, float* __restrict__ h2) {
  __shared__ __align__(16) char smem[131072];
  const int tid = threadIdx.x;
  const int lane = tid & 63, wid = tid >> 6;
  const int wr = wid >> 2, wc = wid & 3;     // 2x4 wave grid; wave owns 128x64 of C

  const int bid = blockIdx.x;
  const int swz = (bid & 7) * 32 + (bid >> 3);   // XCD-aware remap (256 = 8*32)
  const int rowBase = (swz >> 4) * 256;
  const int colBase = (swz & 15) * 256;

  // staging source (per-thread, pre-swizzled column so linear LDS dest = swizzled layout)
  const int srow = tid >> 3;                              // 0..63 within a piece
  const int scolb = ((tid & 7) << 4) ^ ((srow & 7) << 4);
  const unsigned short* pA = A + (size_t)(rowBase + srow) * NN + (scolb >> 1);
  const unsigned short* pB = BT + (size_t)(colBase + srow) * NN + (scolb >> 1);

  // ds_read swizzled column constants
  const int rl = lane & 15;
  const int c0 = ((lane >> 4) << 4) ^ ((lane & 7) << 4);  // kk=0 physical col byte
  const int c1 = c0 ^ 64;                                  // kk=1
  const int aoff = (wr * 128 + rl) * 128;          // A row byte base (mh0,m=0)
  const int boff = 32768 + (wc * 64 + rl) * 128;   // B row byte base

  f32x4 acc[8][4] = {};
  bf16x8 bk0[4], bk1[4], afA[4], afB[4];

  // prologue: stage tile0 -> buf0, drain, preload P1 frags
  {
    char* w0 = smem + (wid << 10);
    GLDS(pB + (size_t)0 * 64 * NN, w0 + 32768 + 0 * 8192);
    GLDS(pB + (size_t)1 * 64 * NN, w0 + 32768 + 1 * 8192);
    GLDS(pB + (size_t)2 * 64 * NN, w0 + 32768 + 2 * 8192);
    GLDS(pB + (size_t)3 * 64 * NN, w0 + 32768 + 3 * 8192);
    GLDS(pA + (size_t)0 * 64 * NN, w0 + 0 * 8192);
    GLDS(pA + (size_t)2 * 64 * NN, w0 + 2 * 8192);
    GLDS(pA + (size_t)1 * 64 * NN, w0 + 1 * 8192);
    GLDS(pA + (size_t)3 * 64 * NN, w0 + 3 * 8192);
    asm volatile("s_waitcnt vmcnt(0)" ::: "memory");
    __builtin_amdgcn_s_barrier();
#pragma unroll
    for (int m = 0; m < 4; ++m) afA[m] = *(const bf16x8*)(smem + aoff + m * 2048 + c0);
#pragma unroll
    for (int n = 0; n < 4; ++n) bk0[n] = *(const bf16x8*)(smem + boff + n * 2048 + c0);
  }

#pragma unroll 2
  for (int t = 0; t < NT; ++t) {
    const char* lb = smem + ((t & 1) << 16);
    char* st = smem + (((t & 1) ^ 1) << 16) + (wid << 10);
    // t=NT-1 stages one tile past the operand end: lands in adjacent workspace
    // regions (audited in kernel_launch), never consumed.
    const unsigned short* s1A = pA + (size_t)(t + 1) * 64;
    const unsigned short* s1B = pB + (size_t)(t + 1) * 64;

    // ---- tile start: stage ALL of t+1 into buf^1 (dead since t-1.P3end fence) ----
    GLDS(s1B + (size_t)0 * 64 * NN, st + 32768 + 0 * 8192);
    GLDS(s1B + (size_t)1 * 64 * NN, st + 32768 + 1 * 8192);
    GLDS(s1B + (size_t)2 * 64 * NN, st + 32768 + 2 * 8192);
    GLDS(s1B + (size_t)3 * 64 * NN, st + 32768 + 3 * 8192);
    GLDS(s1A + (size_t)0 * 64 * NN, st + 0 * 8192);
    GLDS(s1A + (size_t)2 * 64 * NN, st + 2 * 8192);
    GLDS(s1A + (size_t)1 * 64 * NN, st + 1 * 8192);
    GLDS(s1A + (size_t)3 * 64 * NN, st + 3 * 8192);

    // ---- P1: MFMA(mh0,k0) on afA,bk0 [preloaded t-1.P4]; read P2 frags ----
#pragma unroll
    for (int m = 0; m < 4; ++m) afB[m] = *(const bf16x8*)(lb + aoff + m * 2048 + c1);
#pragma unroll
    for (int n = 0; n < 4; ++n) bk1[n] = *(const bf16x8*)(lb + boff + n * 2048 + c1);
    __builtin_amdgcn_s_setprio(1);
#pragma unroll
    for (int m = 0; m < 4; ++m)
#pragma unroll
      for (int n = 0; n < 4; ++n)
        acc[m][n] = __builtin_amdgcn_mfma_f32_16x16x32_bf16(afA[m], bk0[n], acc[m][n], 0, 0, 0);
    __builtin_amdgcn_s_setprio(0);
    asm volatile("s_waitcnt vmcnt(8)" ::: "memory");   // t's A1,A3 landed (issued 1 tile ago)
    __builtin_amdgcn_s_barrier();                      // cross-wave: A-odd(t) visible
    __builtin_amdgcn_sched_barrier(0);

    // ---- P2: MFMA(mh0,k1) on afB,bk1; read P3 frags (A-odd, k0) ----
#pragma unroll
    for (int m = 0; m < 4; ++m) afA[m] = *(const bf16x8*)(lb + aoff + (4 + m) * 2048 + c0);
    __builtin_amdgcn_s_setprio(1);
#pragma unroll
    for (int m = 0; m < 4; ++m)
#pragma unroll
      for (int n = 0; n < 4; ++n)
        acc[m][n] = __builtin_amdgcn_mfma_f32_16x16x32_bf16(afB[m], bk1[n], acc[m][n], 0, 0, 0);
    __builtin_amdgcn_s_setprio(0);
    __builtin_amdgcn_sched_barrier(0);

    // ---- P3: MFMA(mh1,k0) on afA,bk0; read P4 frags (A-odd, k1); tile fence ----
#pragma unroll
    for (int m = 0; m < 4; ++m) afB[m] = *(const bf16x8*)(lb + aoff + (4 + m) * 2048 + c1);
    __builtin_amdgcn_s_setprio(1);
#pragma unroll
    for (int m = 0; m < 4; ++m)
#pragma unroll
      for (int n = 0; n < 4; ++n)
        acc[4 + m][n] = __builtin_amdgcn_mfma_f32_16x16x32_bf16(afA[m], bk0[n], acc[4 + m][n], 0, 0, 0);
    __builtin_amdgcn_s_setprio(0);
    asm volatile("s_waitcnt lgkmcnt(0)" ::: "memory");  // this wave's buf(t) reads retired
    asm volatile("s_waitcnt vmcnt(2)" ::: "memory");    // t+1's early-6 landed
    __builtin_amdgcn_s_barrier();                       // buf(t) may be overwritten next tile
    __builtin_amdgcn_sched_barrier(0);

    // ---- P4: preload next P1 frags from buf^1 (guarded); MFMA(mh1,k1) ----
    {
      const char* nb = smem + (((t + 1) & 1) << 16);
#pragma unroll
      for (int m = 0; m < 4; ++m) afA[m] = *(const bf16x8*)(nb + aoff + m * 2048 + c0);
#pragma unroll
      for (int n = 0; n < 4; ++n) bk0[n] = *(const bf16x8*)(nb + boff + n * 2048 + c0);
    }
    __builtin_amdgcn_s_setprio(1);
#pragma unroll
    for (int m = 0; m < 4; ++m)
#pragma unroll
      for (int n = 0; n < 4; ++n)
        acc[4 + m][n] = __builtin_amdgcn_mfma_f32_16x16x32_bf16(afB[m], bk1[n], acc[4 + m][n], 0, 0, 0);
    __builtin_amdgcn_s_setprio(0);
    __builtin_amdgcn_sched_barrier(0);
  }

  // ---- epilogue ----
  const int orow = rowBase + wr * 128 + (lane >> 4) * 4;
  const int ocol = colBase + wc * 64 + (lane & 15);
  if (EPI == 0) {
#pragma unroll
    for (int n = 0; n < 4; ++n) {
      int ccol = ocol + n * 16;
#pragma unroll
      for (int m = 0; m < 8; ++m) {
#pragma unroll
        for (int i = 0; i < 4; ++i) {
          C[(size_t)(orow + m * 16 + i) * NN + ccol] = (unsigned short)f2bf(acc[m][n][i]);
        }
      }
    }
  } else {
    // x1 = sigmoid(acc + b1[col]); h2[row] += sum_col x1*W2[col]
    float bv[4], wv[4];
#pragma unroll
    for (int n = 0; n < 4; ++n) { bv[n] = bias[ocol + n * 16]; wv[n] = W2[ocol + n * 16]; }
#pragma unroll
    for (int m = 0; m < 8; ++m) {
#pragma unroll
      for (int i = 0; i < 4; ++i) {
        float s = 0.0f;
#pragma unroll
        for (int n = 0; n < 4; ++n) {
          float x = 1.0f / (1.0f + __expf(-(acc[m][n][i] + bv[n])));
          s += x * wv[n];
        }
        s += __shfl_xor(s, 1);
        s += __shfl_xor(s, 2);
        s += __shfl_xor(s, 4);
        s += __shfl_xor(s, 8);
        if ((lane & 15) == 0) atomicAdd(&h2[orow + m * 16 + i], s);
      }
    }
  }
}

// ---------------- layer 2 tail ----------------

__global__ void init_t_kernel(const float* __restrict__ dinv, const float* __restrict__ h2,
                              const float* __restrict__ b2, float* __restrict__ tacc) {
  int v = blockIdx.x * 256 + threadIdx.x;
  if (v < NN) tacc[v] = dinv[v] * dinv[v] * h2[v] + b2[0];
}

__global__ void scatter_t_kernel(const int* __restrict__ src, const int* __restrict__ dst,
                                 int E, const float* __restrict__ dinv,
                                 const float* __restrict__ h2, float* __restrict__ tacc) {
  int e = blockIdx.x * 256 + threadIdx.x;
  if (e < E) {
    int s = src[e], d = dst[e];
    atomicAdd(&tacc[d], dinv[s] * dinv[d] * h2[s]);
  }
}

__global__ void final_kernel(const float* __restrict__ tacc, float* __restrict__ out) {
  int v = blockIdx.x * 256 + threadIdx.x;
  if (v < NN) out[v] = 1.0f / (1.0f + __expf(-tacc[v]));
}

// ---------------- launch ----------------

extern "C" void kernel_launch(void* const* d_in, const int* in_sizes, int n_in,
                              void* d_out, int out_size, void* d_ws, size_t ws_size,
                              hipStream_t stream) {
  const float* x  = (const float*)d_in[0];
  const int*   ei = (const int*)d_in[1];
  const float* W1 = (const float*)d_in[2];
  const float* b1 = (const float*)d_in[3];
  const float* W2 = (const float*)d_in[4];
  const float* b2 = (const float*)d_in[5];
  float* out = (float*)d_out;
  const int E = in_sizes[1] / 2;
  const int* esrc = ei;
  const int* edst = ei + E;

  char* w = (char*)d_ws;
  float*          Sf  = (float*)w;                                  // [0,64M) f32 dense S
  unsigned short* H1T = (unsigned short*)w;                         // [0,32M)  (after Sf dead)
  unsigned short* W1T = (unsigned short*)(w + (size_t)(32u << 20)); // [32M,64M)
  unsigned short* Sbf = (unsigned short*)(w + (size_t)(64u << 20)); // [64M,96M)
  unsigned short* Xbf = (unsigned short*)(w + (size_t)(96u << 20)); // [96M,128M)
  float* deg  = (float*)(w + (size_t)(128u << 20));
  float* dinv = deg + 4096;
  float* h2   = deg + 8192;
  float* tacc = deg + 12288;

  // graph normalization
  init_deg_kernel<<<16, 256, 0, stream>>>(deg);
  count_deg_kernel<<<(E + 255) / 256, 256, 0, stream>>>(edst, E, deg);
  dinv_kernel<<<16, 256, 0, stream>>>(deg, dinv);

  // dense S (f32, atomics sum duplicate edges), then cast to bf16
  hipMemsetAsync(Sf, 0, (size_t)64 << 20, stream);
  hipMemsetAsync(h2, 0, 4096 * sizeof(float), stream);
  diag_kernel<<<16, 256, 0, stream>>>(dinv, Sf);
  scatter_S_kernel<<<(E + 255) / 256, 256, 0, stream>>>(esrc, edst, E, dinv, Sf);
  cast_kernel<<<8192, 256, 0, stream>>>(Sf, Sbf, NN * NN);

  // operand preparation
  cast_kernel<<<8192, 256, 0, stream>>>(x, Xbf, NN * NN);
  transpose_cast_kernel<<<dim3(128, 128), dim3(32, 8), 0, stream>>>(W1, W1T);

  // layer 1: GEMM1 (H1T), then GEMM2 with fused sigmoid + W2 matvec -> h2
  gemm256_kernel<0><<<256, 512, 0, stream>>>(W1T, Xbf, H1T, nullptr, nullptr, nullptr);
  gemm256_kernel<1><<<256, 512, 0, stream>>>(Sbf, H1T, nullptr, b1, W2, h2);

  // layer 2 tail: scalar aggregation + sigmoid
  init_t_kernel<<<16, 256, 0, stream>>>(dinv, h2, b2, tacc);
  scatter_t_kernel<<<(E + 255) / 256, 256, 0, stream>>>(esrc, edst, E, dinv, h2, tacc);
  final_kernel<<<16, 256, 0, stream>>>(tacc, out);
}